// Round 15
// baseline (108.435 us; speedup 1.0000x reference)
//
#include <hip/hip_runtime.h>
#include <stdint.h>

// ContrastiveLoss: B=8192, D=1024, n=2048, T=0.5
// K1: row-normalize f32 -> fp8 e4m3 into MFMA-native 2KB "units"
//     (unit = (row16, kt); lane-l fragment lo16 at l*16, hi16 at 1024+l*16)
// K2: 256x256 MX-fp8 GEMM, 1024 thr (16 waves 4x4, wave=64x64, acc=64),
//     LDS 2x64KB unit-format double buffer, 2-DEEP PIPELINE:
//     per tile {vmcnt(4) gate; s_barrier; compute; s_barrier; stage t+2}.
//     Raw s_barrier (no vmcnt0 drain!) -> loads covered by a full tile.
// K3: scalar finalize

#define BDIM 1024
#define BROWS 8192
#define NROWS 2048
#define NKT 8              // K-tiles of 128 fp8 bytes

typedef __attribute__((ext_vector_type(4))) int i32x4;
typedef __attribute__((ext_vector_type(8))) int i32x8;
typedef __attribute__((ext_vector_type(4))) float f32x4;

// float -> OCP e4m3fn, RNE, handles subnormals (|x| <= 1 for our data)
static __device__ __forceinline__ unsigned char f2e4m3(float x) {
  uint32_t u = __float_as_uint(x);
  uint32_t s = (u >> 24) & 0x80u;
  uint32_t a = u & 0x7fffffffu;
  if (a == 0) return (unsigned char)s;
  int e = (int)(a >> 23) - 127;
  uint32_t m = a & 0x7fffffu;
  if (e >= -6) {
    uint32_t keep = m >> 20;
    uint32_t rest = m & 0xfffffu;
    keep += (rest > 0x80000u) || (rest == 0x80000u && (keep & 1u));
    uint32_t v = ((uint32_t)(e + 7) << 3) + keep;
    return (unsigned char)(s | v);
  }
  if (e < -10) return (unsigned char)s;
  uint32_t full = 0x800000u | m;
  int sh = 14 - e;
  uint32_t keep = full >> sh;
  uint32_t rest = full & ((1u << sh) - 1u);
  uint32_t half = 1u << (sh - 1);
  keep += (rest > half) || (rest == half && (keep & 1u));
  return (unsigned char)(s | keep);
}

static __device__ __forceinline__ void gload_lds16(const unsigned char* g, unsigned char* l) {
  __builtin_amdgcn_global_load_lds(
      (const __attribute__((address_space(1))) uint32_t*)(const void*)g,
      (__attribute__((address_space(3))) uint32_t*)(void*)l,
      16, 0, 0);
}

static __device__ __forceinline__ uint32_t pk4(float4 v, float inv) {
  return (uint32_t)f2e4m3(v.x * inv) | ((uint32_t)f2e4m3(v.y * inv) << 8) |
         ((uint32_t)f2e4m3(v.z * inv) << 16) | ((uint32_t)f2e4m3(v.w * inv) << 24);
}

__global__ __launch_bounds__(256) void normalize_kernel(const float* __restrict__ emb,
                                                        unsigned char* __restrict__ zb,
                                                        float* __restrict__ denom,
                                                        float* __restrict__ sumsim) {
  const int w = threadIdx.x >> 6;
  const int lane = threadIdx.x & 63;
  const int row = blockIdx.x * 4 + w;
  const float4* src = reinterpret_cast<const float4*>(emb + (size_t)row * BDIM);
  float4 v[4];
  float ss = 0.f;
#pragma unroll
  for (int i = 0; i < 4; i++) {
    v[i] = src[lane * 4 + i];
    ss += v[i].x * v[i].x + v[i].y * v[i].y + v[i].z * v[i].z + v[i].w * v[i].w;
  }
#pragma unroll
  for (int m = 1; m < 64; m <<= 1) ss += __shfl_xor(ss, m);
  const float inv = rsqrtf(ss);
  uint4 o;
  o.x = pk4(v[0], inv);
  o.y = pk4(v[1], inv);
  o.z = pk4(v[2], inv);
  o.w = pk4(v[3], inv);
  // unit layout: unit = (row>>4)*8 + (lane>>3); within unit:
  //   half = lane&1, gl = ((lane>>1)&3)*16 + (row&15); off = half*1024 + gl*16
  const size_t unit = (size_t)(row >> 4) * 8 + (lane >> 3);
  const int off = (lane & 1) * 1024 + ((((lane >> 1) & 3) * 16 + (row & 15)) * 16);
  *reinterpret_cast<uint4*>(zb + unit * 2048 + off) = o;
  if (blockIdx.x < NROWS / 4 && lane == 0) denom[row] = 0.f;
  if (blockIdx.x == 0 && threadIdx.x == 0) sumsim[0] = 0.f;
}

// ---------------- GEMM: 2-deep pipelined, unit-format LDS ----------------

__global__ __launch_bounds__(1024) void gemm_fused(const unsigned char* __restrict__ zb,
                                                   float* __restrict__ denom,
                                                   float* __restrict__ sumsim) {
  __shared__ unsigned char As[2 * 16 * 2048];  // 2 x 32 KB (16 A-units each)
  __shared__ unsigned char Bs[2 * 16 * 2048];  // 2 x 32 KB

  // XCD-chunked: xcd owns 4 j-blocks x all 8 i-blocks (A 2MB + B 1MB < 4MB L2)
  const int bx = blockIdx.x;            // 0..255
  const int xcd = bx & 7;
  const int idx = bx >> 3;              // 0..31
  const int jb = xcd * 4 + (idx & 3);   // 0..31
  const int ib = idx >> 2;              // 0..7
  const int i0 = ib * 256;              // [0,2048)
  const int j0 = jb * 256;              // [0,8192)
  const int i16 = i0 >> 4;
  const int j16 = j0 >> 4;

  const int t = threadIdx.x;
  const int lane = t & 63;
  const int w = t >> 6;                 // 0..15
  const int WR = w >> 2;                // 0..3
  const int WC = w & 3;                 // 0..3

  f32x4 acc[4][4] = {};

#define GATE(N) asm volatile("s_waitcnt vmcnt(" #N ")" ::: "memory")
#define BARR() __builtin_amdgcn_s_barrier()
#define SFENCE() __builtin_amdgcn_sched_barrier(0)

  // wave w stages 2 units (4 gloads): w<8 -> A units 2w,2w+1; else B units.
#define STAGE(buf, kt)                                                              \
  {                                                                                 \
    if (w < 8) {                                                                    \
      _Pragma("unroll") for (int uu = 0; uu < 2; ++uu) {                            \
        const int u = 2 * w + uu;                                                   \
        const unsigned char* s0 = zb + (((size_t)(i16 + u)) * 8 + (kt)) * 2048 + lane * 16; \
        unsigned char* d0 = As + (buf) * 32768 + u * 2048;                          \
        gload_lds16(s0, d0);                                                        \
        gload_lds16(s0 + 1024, d0 + 1024);                                          \
      }                                                                             \
    } else {                                                                        \
      _Pragma("unroll") for (int uu = 0; uu < 2; ++uu) {                            \
        const int u = 2 * (w - 8) + uu;                                             \
        const unsigned char* s0 = zb + (((size_t)(j16 + u)) * 8 + (kt)) * 2048 + lane * 16; \
        unsigned char* d0 = Bs + (buf) * 32768 + u * 2048;                          \
        gload_lds16(s0, d0);                                                        \
        gload_lds16(s0 + 1024, d0 + 1024);                                          \
      }                                                                             \
    }                                                                               \
  }

#define RDU(dst, base, u)                                                   \
  {                                                                         \
    const unsigned char* p_ = (base) + (u) * 2048 + lane * 16;              \
    const i32x4 lo_ = *reinterpret_cast<const i32x4*>(p_);                  \
    const i32x4 hi_ = *reinterpret_cast<const i32x4*>(p_ + 1024);           \
    dst[0] = lo_[0]; dst[1] = lo_[1]; dst[2] = lo_[2]; dst[3] = lo_[3];     \
    dst[4] = hi_[0]; dst[5] = hi_[1]; dst[6] = hi_[2]; dst[7] = hi_[3];     \
  }

#define COMPUTE(buf)                                                        \
  {                                                                         \
    const unsigned char* ab = As + (buf) * 32768;                           \
    const unsigned char* bbase = Bs + (buf) * 32768;                        \
    i32x8 bb[4];                                                            \
    _Pragma("unroll") for (int nn = 0; nn < 4; nn++) {                      \
      RDU(bb[nn], bbase, WC * 4 + nn);                                      \
    }                                                                       \
    __builtin_amdgcn_s_setprio(1);                                          \
    _Pragma("unroll") for (int mm = 0; mm < 4; mm++) {                      \
      i32x8 aa;                                                             \
      RDU(aa, ab, WR * 4 + mm);                                             \
      _Pragma("unroll") for (int nn = 0; nn < 4; nn++) {                    \
        acc[mm][nn] = __builtin_amdgcn_mfma_scale_f32_16x16x128_f8f6f4(     \
            aa, bb[nn], acc[mm][nn], 0, 0, 0, 0x7f7f7f7f, 0, 0x7f7f7f7f);   \
      }                                                                     \
    }                                                                       \
    __builtin_amdgcn_s_setprio(0);                                          \
  }

  // ---- prologue: stage tiles 0 and 1 ----
  STAGE(0, 0);
  STAGE(1, 1);

#pragma unroll 1
  for (int kt = 0; kt < 6; ++kt) {
    GATE(4);   // tile kt landed; tile kt+1's 4 loads may still fly
    BARR();
    SFENCE();
    COMPUTE(kt & 1);
    SFENCE();
    BARR();    // all waves done reading buf (kt&1)
    STAGE(kt & 1, kt + 2);
  }
  // kt = 6
  GATE(4);
  BARR();
  SFENCE();
  COMPUTE(0);
  // kt = 7
  GATE(0);
  BARR();
  SFENCE();
  COMPUTE(1);

  // ---- epilogue: C/D layout col=lane&15, row=(lane>>4)*4+reg ----
  const int hi4 = lane >> 4;
  const int col_l = lane & 15;
  float ssim = 0.f;
#pragma unroll
  for (int m = 0; m < 4; m++) {
    const int gibase = i0 + WR * 64 + m * 16 + hi4 * 4;
#pragma unroll
    for (int r = 0; r < 4; r++) {
      const int gi = gibase + r;
      float dsum = 0.f;
#pragma unroll
      for (int n = 0; n < 4; n++) {
        const int gj = j0 + WC * 64 + n * 16 + col_l;
        const float s = acc[m][n][r] * 2.0f;
        const float e = __expf(s);
        if (gj != gi) dsum += e;               // denom excludes diagonal
        if (gj < NROWS && gi < gj) ssim += s;  // triu(rows[:, :n], k=1)
      }
      dsum += __shfl_xor(dsum, 1);
      dsum += __shfl_xor(dsum, 2);
      dsum += __shfl_xor(dsum, 4);
      dsum += __shfl_xor(dsum, 8);
      if (col_l == 0) atomicAdd(&denom[gi], dsum);
    }
  }
#pragma unroll
  for (int msk = 1; msk < 64; msk <<= 1) ssim += __shfl_xor(ssim, msk);
  if (lane == 0 && j0 < NROWS) atomicAdd(sumsim, ssim);
}

__global__ __launch_bounds__(1024) void finalize(const float* __restrict__ denom,
                                                 const float* __restrict__ sumsim,
                                                 float* __restrict__ out) {
  const int t = threadIdx.x;
  double s = 0.0;
#pragma unroll
  for (int i = t; i < NROWS; i += 1024) {
    s += (double)(NROWS - 1 - i) * log((double)denom[i]);
  }
#pragma unroll
  for (int m = 1; m < 64; m <<= 1) s += __shfl_xor(s, m);
  __shared__ double ws_[16];
  if ((t & 63) == 0) ws_[t >> 6] = s;
  __syncthreads();
  if (t == 0) {
    double tot = 0.0;
#pragma unroll
    for (int i = 0; i < 16; i++) tot += ws_[i];
    const double loss = tot - (double)sumsim[0];
    out[0] = (float)(-2.0 / (double)NROWS * (double)(NROWS - 1) * loss);
  }
}

extern "C" void kernel_launch(void* const* d_in, const int* in_sizes, int n_in,
                              void* d_out, int out_size, void* d_ws, size_t ws_size,
                              hipStream_t stream) {
  const float* emb = (const float*)d_in[0];
  unsigned char* zb = (unsigned char*)d_ws;
  float* denom = (float*)((char*)d_ws + (size_t)BROWS * BDIM);  // 8 MB fp8
  float* sumsim = denom + NROWS;
  float* out = (float*)d_out;

  normalize_kernel<<<BROWS / 4, 256, 0, stream>>>(emb, zb, denom, sumsim);
  gemm_fused<<<256, 1024, 0, stream>>>(zb, denom, sumsim);
  finalize<<<1, 1024, 0, stream>>>(denom, sumsim, out);
}